// Round 12
// baseline (153.139 us; speedup 1.0000x reference)
//
#include <hip/hip_runtime.h>

typedef _Float16 half_t;
typedef _Float16 half8 __attribute__((ext_vector_type(8)));
typedef _Float16 half4 __attribute__((ext_vector_type(4)));
typedef float f32x4 __attribute__((ext_vector_type(4)));

#define MFMA32(a, b, c) __builtin_amdgcn_mfma_f32_16x16x32_f16((a), (b), (c), 0, 0, 0)
#define MFMA16(a, b, c) __builtin_amdgcn_mfma_f32_16x16x16f16((a), (b), (c), 0, 0, 0)

static constexpr int kM  = 512;
static constexpr int kD  = 64;
static constexpr int kKL = 2560;
static constexpr int kL  = 2048;
// ws (halves): q_scaled | K [bh][k][d] | Vc chunked [bh][80][64][32] | peT [l][d] | zm (f32)
static constexpr int WS_QS  = 0;                    // 1,048,576
static constexpr int WS_KB  = 1048576;              // 5,242,880
static constexpr int WS_VC  = WS_KB + 5242880;      // 5,242,880
static constexpr int WS_PET = WS_VC + 5242880;      // 131,072
static constexpr int WS_Z   = WS_PET + 131072;      // 16384 f32 used (zeroed region 128KB)

// ---------- K1: q/k convert + V chunked-transpose + pe transpose + zero out/z ----------
__global__ __launch_bounds__(256) void prep_kernel(const float* __restrict__ q,
    const float* __restrict__ k, const float* __restrict__ v,
    const float* __restrict__ pe, half_t* __restrict__ ws, float* __restrict__ out) {
  __shared__ float ls[64 * 72];
  const int b = blockIdx.x, t = threadIdx.x;
  if (b < 3072) {
    const int i = b * 256 + t;
    const float QS = 0.125f * 1.4426950408889634f;  // 1/sqrt(64) * log2(e)
    const float* src; half_t* dst; float sc;
    if (i < 131072) { src = q + (size_t)i * 8; dst = ws + WS_QS + (size_t)i * 8; sc = QS; }
    else { const int j = i - 131072; src = k + (size_t)j * 8; dst = ws + WS_KB + (size_t)j * 8; sc = 1.0f; }
    const float4 a = ((const float4*)src)[0];
    const float4 bb = ((const float4*)src)[1];
    half_t tt[8];
    tt[0] = (half_t)(a.x * sc);  tt[1] = (half_t)(a.y * sc);
    tt[2] = (half_t)(a.z * sc);  tt[3] = (half_t)(a.w * sc);
    tt[4] = (half_t)(bb.x * sc); tt[5] = (half_t)(bb.y * sc);
    tt[6] = (half_t)(bb.z * sc); tt[7] = (half_t)(bb.w * sc);
    *(int4*)dst = *(int4*)tt;
    return;
  }
  if (b >= 4384) {
    if (b < 4640) {                       // zero d_out
      float4* o = (float4*)out;
      const int base = (b - 4384) * 1024 + t;
#pragma unroll
      for (int u = 0; u < 4; ++u) o[base + u * 256] = float4{0, 0, 0, 0};
    } else {                              // zero z region
      float4* z = (float4*)((float*)(ws + WS_Z));
      const int base = (b - 4640) * 1024 + t;
#pragma unroll
      for (int u = 0; u < 4; ++u) z[base + u * 256] = float4{0, 0, 0, 0};
    }
    return;
  }
  const bool isV = (b < 4352);
  int bh = 0, kt = 0, b3 = 0;
  const float* src; int sstride;
  if (isV) {
    const int b2 = b - 3072;
    bh = b2 / 40; kt = b2 % 40;
    src = v + (size_t)(bh * 2560 + kt * 64) * 64; sstride = 64;
  } else {
    b3 = b - 4352;
    src = pe + (size_t)b3 * 64; sstride = 2048;
  }
  const int rr = t >> 4, cq = (t & 15) * 4;
#pragma unroll
  for (int p = 0; p < 4; ++p) {
    const float4 x = *(const float4*)(src + (size_t)(p * 16 + rr) * sstride + cq);
    *(float4*)(ls + (p * 16 + rr) * 72 + cq) = x;
  }
  __syncthreads();
  const int oc = t >> 2, ch = t & 3;
  half_t tmp[16];
#pragma unroll
  for (int i2 = 0; i2 < 16; ++i2) tmp[i2] = (half_t)ls[(ch * 16 + i2) * 72 + oc];
  half_t* o;
  if (isV) {
    o = ws + WS_VC + (size_t)bh * 163840 + ((kt << 1) + (ch >> 1)) * 2048 + oc * 32 + ((ch & 1) << 4);
  } else {
    o = ws + WS_PET + ((size_t)b3 * 64 + oc) * 64 + ch * 16;
  }
  ((int4*)o)[0] = ((int4*)tmp)[0];
  ((int4*)o)[1] = ((int4*)tmp)[1];
}

// ---------- K2: split-K attention, premultiplied-mask bias strips ----------
// grid 1024 = 32bh x 4 m-blocks(128 rows) x 8 K-splits (9/9/9/9/8/8/8/8 chunks);
// block 256 (4 waves), wave owns 32 rows as 2 m-frags.
// Strip stores Em(l,c) = exp2(bias)*mask*valid as f16, layout [c][u=l+c] stride 68
// -> softmax hot loop is: aligned ds_read_b64 + pm = exp2(s)*Em. All mask /
// bounds / bias-add work moved to the (off-critical) window-write side, where
// exp2(bias) is a 3-fma polynomial (|bias|<=~0.15) and classification is
// wave-uniform per window. 1e-8*zal regularizer dropped (rel. effect ~1e-7).
// LDS: K 2x4608B | Vc 2x5120B | strips 8x2176B = 36,864B -> 4 blocks/CU.
__global__ __launch_bounds__(256, 3) void attn_kernel(
    const half_t* __restrict__ ws, const float* __restrict__ cvp,
    float* __restrict__ out, float* __restrict__ zmA) {

  __shared__ __align__(16) char smem[36864];
  half_t* lsh = (half_t*)smem;

  const int tid  = threadIdx.x;
  const int lane = tid & 63;
  const int w    = tid >> 6;                    // wave 0..3
  const int c    = lane & 15;
  const int qd   = lane >> 4;

  const int id = blockIdx.x;                    // 1024
  const int bh = ((id & 7) << 2) | (id >> 8);   // XCD-aware
  const int mid = (id >> 3) & 31;
  const int mb = mid & 3, sp = mid >> 2;
  const int m0 = mb << 7;                       // 128 rows per block
  const int g0   = (sp < 4) ? sp * 9 : 36 + (sp - 4) * 8;
  const int tmax = (sp < 4) ? 9 : 8;            // 68 chunks total

  const float cvl = cvp[bh & 7] * 2048.0f - 2047.0f;  // mask = clamp((l+cvl)/64+1,0,1)
  const float cvO = cvl * 0.015625f + 1.0f;           // mask = clamp(l/64 + cvO, 0, 1)

  const half_t* kb  = ws + WS_KB + (size_t)bh * (kKL * kD);
  const half_t* vcb = ws + WS_VC + (size_t)bh * (kKL * kD);
  const half_t* pet = ws + WS_PET;

  // Q B-frags for the wave's 2 m-frags (rows m0+32w+16f+c)
  half8 bq0[2], bq1[2];
#pragma unroll
  for (int f = 0; f < 2; ++f) {
    const half_t* qrow = ws + WS_QS + (size_t)(bh * kM + m0 + 32 * w + 16 * f + c) * kD;
    bq0[f] = *(const half8*)(qrow + qd * 8);
    bq1[f] = *(const half8*)(qrow + 32 + qd * 8);
  }

  // LDS (halves): K ring 2x2304 @0 | Vc ring 2x2560 @4608 | strips 8x1088 @9728
  int4 stgK, stgV;
  auto issueKV = [&](int gg) {
    const int r = tid >> 3, seg = tid & 7;
    const int krow = m0 + (gg << 5) + r;               // max 2559: no clamp needed
    stgK = *(const int4*)(kb + (size_t)krow * kD + seg * 8);
    const int vch = (m0 >> 5) + gg;                    // max 79: no clamp needed
    stgV = *(const int4*)(vcb + (size_t)vch * 2048 + tid * 8);
  };
  auto commitKV = [&](int gg) {
    const int sK = (gg & 1) * 2304;
    const int sV = 4608 + (gg & 1) * 2560;
    const int r = tid >> 3, seg = tid & 7;
    *(int4*)(lsh + sK + r * 72 + seg * 8) = stgK;
    const int d = tid >> 2, ks = (tid & 3) * 8;
    *(int4*)(lsh + sV + d * 40 + ks) = stgV;
  };

  // window write: bias acc 'a' (l = wb+qd*4+reg, query c) -> Em into strip f
  auto stripWrite = [&](int f, int wb, const f32x4& a) {
    half_t* stf = lsh + 9728 + (w * 2 + f) * 1088 + c * 68;
    const int allone  = (wb >= 0) && (wb + 15 <= kL - 1) && (wb + cvl >= 0.0f);
    const int allzero = (wb > kL - 1) || (wb + 15 < 0) || ((float)(wb + 15) + cvl <= -64.0f);
#pragma unroll
    for (int reg = 0; reg < 4; ++reg) {
      const int l = wb + qd * 4 + reg;
      const float bt = a[reg] * 0.6931472f;
      // exp2(b) = e^(b ln2) ~ 1 + t + t^2/2 + t^3/6, |t| <= ~0.11
      float e = __builtin_fmaf(bt, 0.16666667f, 0.5f);
      e = __builtin_fmaf(e, bt, 1.0f);
      e = __builtin_fmaf(e, bt, 1.0f);
      float em;
      if (allzero) em = 0.0f;
      else if (allone) em = e;
      else {
        const float mk = fminf(fmaxf((float)l * 0.015625f + cvO, 0.0f), 1.0f);
        em = ((unsigned)l < (unsigned)kL) ? e * mk : 0.0f;
      }
      stf[(l + c) & 63] = (half_t)em;
    }
  };
  auto peWindow = [&](int wb, f32x4& accf0, f32x4& accf1, bool dof0, bool dof1) {
    int l = wb + c; l = l < 0 ? 0 : (l > kL - 1 ? kL - 1 : l);
    const half8 p0 = *(const half8*)(pet + (size_t)l * kD + qd * 8);
    const half8 p1 = *(const half8*)(pet + (size_t)l * kD + 32 + qd * 8);
    if (dof0) { f32x4 a = {0,0,0,0}; a = MFMA32(p0, bq0[0], a); accf0 = MFMA32(p1, bq1[0], a); }
    if (dof1) { f32x4 a = {0,0,0,0}; a = MFMA32(p0, bq0[1], a); accf1 = MFMA32(p1, bq1[1], a); }
  };

  // ---- prime: K/V chunk g0 + 4 bias windows ----
  issueKV(g0);
  const int B0 = (g0 << 5) - 32 * w;
#pragma unroll
  for (int k4 = 0; k4 < 4; ++k4) {
    const int wb = B0 + 16 - (k4 << 4);
    f32x4 a0, a1;
    const bool d0 = (k4 <= 2), d1 = (k4 >= 1);
    peWindow(wb, a0, a1, d0, d1);
    if (d0) stripWrite(0, wb, a0);
    if (d1) stripWrite(1, wb, a1);
  }
  commitKV(g0);
  __syncthreads();

  float zmc[2] = {0, 0};
  f32x4 o[2][4];
#pragma unroll
  for (int f = 0; f < 2; ++f)
#pragma unroll
    for (int dc = 0; dc < 4; ++dc) o[f][dc] = f32x4{0, 0, 0, 0};

  for (int t = 0; t < tmax; ++t) {
    const int g = g0 + t;
    const bool more = (t + 1 < tmax);
    if (more) issueKV(g + 1);

    const int sK = (g & 1) * 2304;
    const int sV = 4608 + (g & 1) * 2560;
    const int B = (g << 5) - 32 * w;             // frag0 l-base

    // K A-frags (shared by both m-frags)
    const half8 ak00 = *(const half8*)(lsh + sK + c * 72 + qd * 8);
    const half8 ak01 = *(const half8*)(lsh + sK + c * 72 + 32 + qd * 8);
    const half8 ak10 = *(const half8*)(lsh + sK + (16 + c) * 72 + qd * 8);
    const half8 ak11 = *(const half8*)(lsh + sK + (16 + c) * 72 + 32 + qd * 8);

    // ---- per-frag: S^T -> pm = exp2(s)*Em -> PV ----
#pragma unroll
    for (int f = 0; f < 2; ++f) {
      f32x4 s0 = {0, 0, 0, 0}, s1 = {0, 0, 0, 0};
      s0 = MFMA32(ak00, bq0[f], s0); s0 = MFMA32(ak01, bq1[f], s0);
      s1 = MFMA32(ak10, bq0[f], s1); s1 = MFMA32(ak11, bq1[f], s1);

      const int base_f = B - 16 * f;
      const half_t* stf = lsh + 9728 + (w * 2 + f) * 1088 + c * 68;
      const half4 em0 = *(const half4*)(stf + ((base_f + qd * 4) & 63));
      const half4 em1 = *(const half4*)(stf + ((base_f + 16 + qd * 4) & 63));

      float pm0[4], pm1[4];
#pragma unroll
      for (int reg = 0; reg < 4; ++reg) {
        pm0[reg] = __builtin_amdgcn_exp2f(s0[reg]) * (float)em0[reg];
        pm1[reg] = __builtin_amdgcn_exp2f(s1[reg]) * (float)em1[reg];
        zmc[f] += pm0[reg] + pm1[reg];
      }
      const half4 pb0h = { (half_t)pm0[0], (half_t)pm0[1], (half_t)pm0[2], (half_t)pm0[3] };
      const half4 pb1h = { (half_t)pm1[0], (half_t)pm1[1], (half_t)pm1[2], (half_t)pm1[3] };
#pragma unroll
      for (int dc = 0; dc < 4; ++dc) {
        const half4 av0 = *(const half4*)(lsh + sV + (dc * 16 + c) * 40 + qd * 4);
        const half4 av1 = *(const half4*)(lsh + sV + (dc * 16 + c) * 40 + 16 + qd * 4);
        o[f][dc] = MFMA16(av0, pb0h, o[f][dc]);
        o[f][dc] = MFMA16(av1, pb1h, o[f][dc]);
      }
    }

    // ---- Em windows for t+1 (after strip reads): wb = B+48, B+32, B+16 ----
    if (more) {
#pragma unroll
      for (int k3 = 0; k3 < 3; ++k3) {
        const int wb = B + 48 - (k3 << 4);
        f32x4 a0, a1;
        const bool d0 = (k3 <= 1), d1 = (k3 >= 1);
        peWindow(wb, a0, a1, d0, d1);
        if (d0) stripWrite(0, wb, a0);
        if (d1) stripWrite(1, wb, a1);
      }
      commitKV(g + 1);
    }
    __syncthreads();
  }

  // ---- epilogue: zm atomics + O via LDS transpose + coalesced atomicAdd ----
  __syncthreads();                              // protect shared K/V from overlay
  float* Ow = (float*)smem + (size_t)w * 2176;  // [32 rows][stride 68] f32
#pragma unroll
  for (int f = 0; f < 2; ++f)
#pragma unroll
    for (int dc = 0; dc < 4; ++dc)
      *(f32x4*)(Ow + (16 * f + c) * 68 + dc * 16 + qd * 4) = o[f][dc];

#pragma unroll
  for (int f = 0; f < 2; ++f) {
    float m = zmc[f];
    m += __shfl_xor(m, 16); m += __shfl_xor(m, 32);
    if (lane < 16) {
      const int row = bh * kM + m0 + 32 * w + 16 * f + c;
      atomicAdd(&zmA[row], m);
    }
  }
  const int rowbase = bh * kM + m0 + 32 * w;
  for (int rr = 0; rr < 32; ++rr)
    atomicAdd(out + (size_t)(rowbase + rr) * kD + lane, Ow[rr * 68 + lane]);
}

// ---------- K3: normalize ----------
__global__ __launch_bounds__(256) void norm_kernel(const float* __restrict__ zmA,
    float* __restrict__ out) {
  const int i = blockIdx.x * 256 + threadIdx.x;   // 262,144
  const int row = i >> 4, d4 = (i & 15) << 2;
  const float inv = 1.0f / (zmA[row] + 1e-20f);
  float4* p = (float4*)(out + (size_t)row * 64 + d4);
  float4 v = *p;
  v.x *= inv; v.y *= inv; v.z *= inv; v.w *= inv;
  *p = v;
}

extern "C" void kernel_launch(void* const* d_in, const int* in_sizes, int n_in,
                              void* d_out, int out_size, void* d_ws, size_t ws_size,
                              hipStream_t stream) {
  (void)in_sizes; (void)n_in; (void)out_size; (void)ws_size;
  const float* q  = (const float*)d_in[0];
  const float* k  = (const float*)d_in[1];
  const float* v  = (const float*)d_in[2];
  const float* pe = (const float*)d_in[3];
  const float* cv = (const float*)d_in[4];
  half_t* ws = (half_t*)d_ws;   // needs ~23.6 MB
  float* out = (float*)d_out;
  float* zmA = (float*)(ws + WS_Z);

  prep_kernel<<<4648, 256, 0, stream>>>(q, k, v, pe, ws, out);
  attn_kernel<<<1024, 256, 0, stream>>>(ws, cv, out, zmA);
  norm_kernel<<<1024, 256, 0, stream>>>(zmA, out);
}

// Round 13
// 147.683 us; speedup vs baseline: 1.0369x; 1.0369x over previous
//
#include <hip/hip_runtime.h>

typedef _Float16 half_t;
typedef _Float16 half8 __attribute__((ext_vector_type(8)));
typedef _Float16 half4 __attribute__((ext_vector_type(4)));
typedef float f32x4 __attribute__((ext_vector_type(4)));

#define MFMA32(a, b, c) __builtin_amdgcn_mfma_f32_16x16x32_f16((a), (b), (c), 0, 0, 0)
#define MFMA16(a, b, c) __builtin_amdgcn_mfma_f32_16x16x16f16((a), (b), (c), 0, 0, 0)

static constexpr int kM  = 512;
static constexpr int kD  = 64;
static constexpr int kKL = 2560;
static constexpr int kL  = 2048;
// ws (halves): q_scaled | K [bh][k][d] | Vc chunked [bh][80][64][32] | peT [l][d] | zm (f32)
static constexpr int WS_QS  = 0;                    // 1,048,576
static constexpr int WS_KB  = 1048576;              // 5,242,880
static constexpr int WS_VC  = WS_KB + 5242880;      // 5,242,880
static constexpr int WS_PET = WS_VC + 5242880;      // 131,072
static constexpr int WS_Z   = WS_PET + 131072;      // 16384 f32 used (zeroed region 128KB)

// ---------- K1: q/k convert + V chunked-transpose + pe transpose + zero out/z ----------
__global__ __launch_bounds__(256) void prep_kernel(const float* __restrict__ q,
    const float* __restrict__ k, const float* __restrict__ v,
    const float* __restrict__ pe, half_t* __restrict__ ws, float* __restrict__ out) {
  __shared__ float ls[64 * 72];
  const int b = blockIdx.x, t = threadIdx.x;
  if (b < 3072) {
    const int i = b * 256 + t;
    const float QS = 0.125f * 1.4426950408889634f;  // 1/sqrt(64) * log2(e)
    const float* src; half_t* dst; float sc;
    if (i < 131072) { src = q + (size_t)i * 8; dst = ws + WS_QS + (size_t)i * 8; sc = QS; }
    else { const int j = i - 131072; src = k + (size_t)j * 8; dst = ws + WS_KB + (size_t)j * 8; sc = 1.0f; }
    const float4 a = ((const float4*)src)[0];
    const float4 bb = ((const float4*)src)[1];
    half_t tt[8];
    tt[0] = (half_t)(a.x * sc);  tt[1] = (half_t)(a.y * sc);
    tt[2] = (half_t)(a.z * sc);  tt[3] = (half_t)(a.w * sc);
    tt[4] = (half_t)(bb.x * sc); tt[5] = (half_t)(bb.y * sc);
    tt[6] = (half_t)(bb.z * sc); tt[7] = (half_t)(bb.w * sc);
    *(int4*)dst = *(int4*)tt;
    return;
  }
  if (b >= 4384) {
    if (b < 4640) {                       // zero d_out
      float4* o = (float4*)out;
      const int base = (b - 4384) * 1024 + t;
#pragma unroll
      for (int u = 0; u < 4; ++u) o[base + u * 256] = float4{0, 0, 0, 0};
    } else {                              // zero z region
      float4* z = (float4*)((float*)(ws + WS_Z));
      const int base = (b - 4640) * 1024 + t;
#pragma unroll
      for (int u = 0; u < 4; ++u) z[base + u * 256] = float4{0, 0, 0, 0};
    }
    return;
  }
  const bool isV = (b < 4352);
  int bh = 0, kt = 0, b3 = 0;
  const float* src; int sstride;
  if (isV) {
    const int b2 = b - 3072;
    bh = b2 / 40; kt = b2 % 40;
    src = v + (size_t)(bh * 2560 + kt * 64) * 64; sstride = 64;
  } else {
    b3 = b - 4352;
    src = pe + (size_t)b3 * 64; sstride = 2048;
  }
  const int rr = t >> 4, cq = (t & 15) * 4;
#pragma unroll
  for (int p = 0; p < 4; ++p) {
    const float4 x = *(const float4*)(src + (size_t)(p * 16 + rr) * sstride + cq);
    *(float4*)(ls + (p * 16 + rr) * 72 + cq) = x;
  }
  __syncthreads();
  const int oc = t >> 2, ch = t & 3;
  half_t tmp[16];
#pragma unroll
  for (int i2 = 0; i2 < 16; ++i2) tmp[i2] = (half_t)ls[(ch * 16 + i2) * 72 + oc];
  half_t* o;
  if (isV) {
    o = ws + WS_VC + (size_t)bh * 163840 + ((kt << 1) + (ch >> 1)) * 2048 + oc * 32 + ((ch & 1) << 4);
  } else {
    o = ws + WS_PET + ((size_t)b3 * 64 + oc) * 64 + ch * 16;
  }
  ((int4*)o)[0] = ((int4*)tmp)[0];
  ((int4*)o)[1] = ((int4*)tmp)[1];
}

// ---------- K2: 1-frag-per-wave, 8-wave-block split-K attention ----------
// grid 768 = 32bh x 4 m-blocks(128 rows) x 6 K-splits (12/12/11/11/11/11 chunks);
// block 512 (8 waves), wave w owns 16 rows (ONE m-frag) -> live set ~70 VGPR,
// so __launch_bounds__(512,6) (budget 85) gives 6 waves/SIMD = 24 waves/CU.
// 768 blocks = exactly 3 resident blocks/CU: full residency, no tail round.
// K/Vc staged once per block (512 thr x int4), shared by all 8 waves; Em bias
// strips wave-private (2 new windows/step/wave = same per-frag cost as R12).
// R10's version of this failed ONLY on VGPR (2-frag live set vs 64-cap ->
// spills); 1-frag live set fits the 6-wave budget.
// LDS: K 2x4608B | Vc 2x5120B | strips 8x2176B = 36,864B.
__global__ __launch_bounds__(512, 6) void attn_kernel(
    const half_t* __restrict__ ws, const float* __restrict__ cvp,
    float* __restrict__ out, float* __restrict__ zmA) {

  __shared__ __align__(16) char smem[36864];
  half_t* lsh = (half_t*)smem;

  const int tid  = threadIdx.x;
  const int lane = tid & 63;
  const int w    = tid >> 6;                    // wave 0..7
  const int c    = lane & 15;
  const int qd   = lane >> 4;

  const int id = blockIdx.x;                    // 768
  const int x  = id & 7;                        // XCD
  const int y  = id >> 3;                       // 0..95
  const int bh = (x << 2) | (y / 24);
  const int r2 = y % 24;
  const int mb = r2 / 6, sp = r2 % 6;
  const int m0 = mb << 7;                       // 128 rows per block
  const int g0   = (sp < 2) ? sp * 12 : 24 + (sp - 2) * 11;
  const int tmax = (sp < 2) ? 12 : 11;          // 68 chunks total

  const float cvl = cvp[bh & 7] * 2048.0f - 2047.0f;  // mask = clamp((l+cvl)/64+1,0,1)
  const float cvO = cvl * 0.015625f + 1.0f;           // mask = clamp(l/64 + cvO, 0, 1)

  const half_t* kb  = ws + WS_KB + (size_t)bh * (kKL * kD);
  const half_t* vcb = ws + WS_VC + (size_t)bh * (kKL * kD);
  const half_t* pet = ws + WS_PET;

  // Q B-frag for the wave's single m-frag (rows m0+16w+c)
  const half_t* qrow = ws + WS_QS + (size_t)(bh * kM + m0 + 16 * w + c) * kD;
  const half8 bq0 = *(const half8*)(qrow + qd * 8);
  const half8 bq1 = *(const half8*)(qrow + 32 + qd * 8);

  // LDS (halves): K ring 2x2304 @0 | Vc ring 2x2560 @4608 | strips 8x1088 @9728
  int4 stg;
  auto issueKV = [&](int gg) {
    if (w < 4) {                                     // waves 0-3: K chunk (4KB)
      const int r = tid >> 3, seg = tid & 7;
      const int krow = m0 + (gg << 5) + r;           // max 2559
      stg = *(const int4*)(kb + (size_t)krow * kD + seg * 8);
    } else {                                         // waves 4-7: V chunk (4KB)
      const int i = tid - 256;
      const int vch = (m0 >> 5) + gg;                // max 79
      stg = *(const int4*)(vcb + (size_t)vch * 2048 + i * 8);
    }
  };
  auto commitKV = [&](int gg) {
    if (w < 4) {
      const int sK = (gg & 1) * 2304;
      const int r = tid >> 3, seg = tid & 7;
      *(int4*)(lsh + sK + r * 72 + seg * 8) = stg;
    } else {
      const int sV = 4608 + (gg & 1) * 2560;
      const int i = tid - 256;
      const int d = i >> 2, ks = (i & 3) * 8;
      *(int4*)(lsh + sV + d * 40 + ks) = stg;
    }
  };

  // window write: bias acc 'a' (l = wb+qd*4+reg, query c) -> Em strip
  half_t* stf = lsh + 9728 + w * 1088 + c * 68;      // wave-private [c][u mod 64]
  auto stripWrite = [&](int wb, const f32x4& a) {
    const int allone  = (wb >= 0) && (wb + 15 <= kL - 1) && (wb + cvl >= 0.0f);
    const int allzero = (wb > kL - 1) || (wb + 15 < 0) || ((float)(wb + 15) + cvl <= -64.0f);
#pragma unroll
    for (int reg = 0; reg < 4; ++reg) {
      const int l = wb + qd * 4 + reg;
      const float bt = a[reg] * 0.6931472f;
      // exp2(b) ~ 1 + t + t^2/2 + t^3/6, |t| <= ~0.11
      float e = __builtin_fmaf(bt, 0.16666667f, 0.5f);
      e = __builtin_fmaf(e, bt, 1.0f);
      e = __builtin_fmaf(e, bt, 1.0f);
      float em;
      if (allzero) em = 0.0f;
      else if (allone) em = e;
      else {
        const float mk = fminf(fmaxf((float)l * 0.015625f + cvO, 0.0f), 1.0f);
        em = ((unsigned)l < (unsigned)kL) ? e * mk : 0.0f;
      }
      stf[(l + c) & 63] = (half_t)em;
    }
  };
  auto peWindow = [&](int wb) -> f32x4 {
    int l = wb + c; l = l < 0 ? 0 : (l > kL - 1 ? kL - 1 : l);
    const half8 p0 = *(const half8*)(pet + (size_t)l * kD + qd * 8);
    const half8 p1 = *(const half8*)(pet + (size_t)l * kD + 32 + qd * 8);
    f32x4 a = {0, 0, 0, 0};
    a = MFMA32(p0, bq0, a);
    return MFMA32(p1, bq1, a);
  };

  // ---- prime: K/V chunk g0 + 3 bias windows (coverage [B0-16, B0+31]) ----
  issueKV(g0);
  const int B0 = (g0 << 5) - 16 * w;
#pragma unroll
  for (int k3 = 0; k3 < 3; ++k3) {
    const int wb = B0 - 16 + (k3 << 4);
    stripWrite(wb, peWindow(wb));
  }
  commitKV(g0);
  __syncthreads();

  float zmc = 0.0f;
  f32x4 o0 = {0,0,0,0}, o1 = {0,0,0,0}, o2 = {0,0,0,0}, o3 = {0,0,0,0};

  for (int t = 0; t < tmax; ++t) {
    const int g = g0 + t;
    const bool more = (t + 1 < tmax);
    if (more) issueKV(g + 1);

    const int sK = (g & 1) * 2304;
    const int sV = 4608 + (g & 1) * 2560;
    const int base = (g << 5) - 16 * w;          // frag l-base

    // K A-frags
    const half8 ak00 = *(const half8*)(lsh + sK + c * 72 + qd * 8);
    const half8 ak01 = *(const half8*)(lsh + sK + c * 72 + 32 + qd * 8);
    const half8 ak10 = *(const half8*)(lsh + sK + (16 + c) * 72 + qd * 8);
    const half8 ak11 = *(const half8*)(lsh + sK + (16 + c) * 72 + 32 + qd * 8);

    // ---- S^T -> pm = exp2(s)*Em -> PV ----
    f32x4 s0 = {0, 0, 0, 0}, s1 = {0, 0, 0, 0};
    s0 = MFMA32(ak00, bq0, s0); s0 = MFMA32(ak01, bq1, s0);
    s1 = MFMA32(ak10, bq0, s1); s1 = MFMA32(ak11, bq1, s1);

    const half4 em0 = *(const half4*)(stf + ((base + qd * 4) & 63));
    const half4 em1 = *(const half4*)(stf + ((base + 16 + qd * 4) & 63));

    float pm0[4], pm1[4];
#pragma unroll
    for (int reg = 0; reg < 4; ++reg) {
      pm0[reg] = __builtin_amdgcn_exp2f(s0[reg]) * (float)em0[reg];
      pm1[reg] = __builtin_amdgcn_exp2f(s1[reg]) * (float)em1[reg];
      zmc += pm0[reg] + pm1[reg];
    }
    const half4 pb0h = { (half_t)pm0[0], (half_t)pm0[1], (half_t)pm0[2], (half_t)pm0[3] };
    const half4 pb1h = { (half_t)pm1[0], (half_t)pm1[1], (half_t)pm1[2], (half_t)pm1[3] };
#pragma unroll
    for (int dc = 0; dc < 4; ++dc) {
      const half4 av0 = *(const half4*)(lsh + sV + (dc * 16 + c) * 40 + qd * 4);
      const half4 av1 = *(const half4*)(lsh + sV + (dc * 16 + c) * 40 + 16 + qd * 4);
      f32x4& od = (dc == 0) ? o0 : (dc == 1) ? o1 : (dc == 2) ? o2 : o3;
      od = MFMA16(av0, pb0h, od);
      od = MFMA16(av1, pb1h, od);
    }

    // ---- Em windows for t+1 (after strip reads): wb = base+32, base+48 ----
    if (more) {
      const int wb1 = base + 32, wb2 = base + 48;
      stripWrite(wb1, peWindow(wb1));
      stripWrite(wb2, peWindow(wb2));
      commitKV(g + 1);
    }
    __syncthreads();
  }

  // ---- epilogue: zm atomics + O via LDS transpose + coalesced atomicAdd ----
  __syncthreads();                              // protect shared K/V from overlay
  float* Ow = (float*)smem + (size_t)w * 1088;  // [16 rows][stride 68] f32
  *(f32x4*)(Ow + c * 68 + 0  + qd * 4) = o0;
  *(f32x4*)(Ow + c * 68 + 16 + qd * 4) = o1;
  *(f32x4*)(Ow + c * 68 + 32 + qd * 4) = o2;
  *(f32x4*)(Ow + c * 68 + 48 + qd * 4) = o3;

  float m = zmc;
  m += __shfl_xor(m, 16); m += __shfl_xor(m, 32);
  if (lane < 16) {
    const int row = bh * kM + m0 + 16 * w + c;
    atomicAdd(&zmA[row], m);
  }
  const int rowbase = bh * kM + m0 + 16 * w;
  for (int rr = 0; rr < 16; ++rr)
    atomicAdd(out + (size_t)(rowbase + rr) * kD + lane, Ow[rr * 68 + lane]);
}

// ---------- K3: normalize ----------
__global__ __launch_bounds__(256) void norm_kernel(const float* __restrict__ zmA,
    float* __restrict__ out) {
  const int i = blockIdx.x * 256 + threadIdx.x;   // 262,144
  const int row = i >> 4, d4 = (i & 15) << 2;
  const float inv = 1.0f / (zmA[row] + 1e-20f);
  float4* p = (float4*)(out + (size_t)row * 64 + d4);
  float4 v = *p;
  v.x *= inv; v.y *= inv; v.z *= inv; v.w *= inv;
  *p = v;
}

extern "C" void kernel_launch(void* const* d_in, const int* in_sizes, int n_in,
                              void* d_out, int out_size, void* d_ws, size_t ws_size,
                              hipStream_t stream) {
  (void)in_sizes; (void)n_in; (void)out_size; (void)ws_size;
  const float* q  = (const float*)d_in[0];
  const float* k  = (const float*)d_in[1];
  const float* v  = (const float*)d_in[2];
  const float* pe = (const float*)d_in[3];
  const float* cv = (const float*)d_in[4];
  half_t* ws = (half_t*)d_ws;   // needs ~23.6 MB
  float* out = (float*)d_out;
  float* zmA = (float*)(ws + WS_Z);

  prep_kernel<<<4648, 256, 0, stream>>>(q, k, v, pe, ws, out);
  attn_kernel<<<768, 512, 0, stream>>>(ws, cv, out, zmA);
  norm_kernel<<<1024, 256, 0, stream>>>(zmA, out);
}

// Round 14
// 137.406 us; speedup vs baseline: 1.1145x; 1.0748x over previous
//
#include <hip/hip_runtime.h>

typedef _Float16 half_t;
typedef _Float16 half8 __attribute__((ext_vector_type(8)));
typedef _Float16 half4 __attribute__((ext_vector_type(4)));
typedef float f32x4 __attribute__((ext_vector_type(4)));
typedef float f32x16 __attribute__((ext_vector_type(16)));

#define MFMA_S(a, b, c) __builtin_amdgcn_mfma_f32_32x32x16_f16((a), (b), (c), 0, 0, 0)

static constexpr int kM  = 512;
static constexpr int kD  = 64;
static constexpr int kKL = 2560;
static constexpr int kL  = 2048;
// ws (halves): q_scaled | K [bh][k][d] | Vc chunked [bh][80][64][32] | peT [l][d] | zm (f32)
static constexpr int WS_QS  = 0;                    // 1,048,576
static constexpr int WS_KB  = 1048576;              // 5,242,880
static constexpr int WS_VC  = WS_KB + 5242880;      // 5,242,880
static constexpr int WS_PET = WS_VC + 5242880;      // 131,072
static constexpr int WS_Z   = WS_PET + 131072;      // zeroed region (zm uses 64KB)

// ---------- K1: q/k convert + V chunked-transpose + pe transpose + zero out/z ----------
__global__ __launch_bounds__(256) void prep_kernel(const float* __restrict__ q,
    const float* __restrict__ k, const float* __restrict__ v,
    const float* __restrict__ pe, half_t* __restrict__ ws, float* __restrict__ out) {
  __shared__ float ls[64 * 72];
  const int b = blockIdx.x, t = threadIdx.x;
  if (b < 3072) {
    const int i = b * 256 + t;
    const float QS = 0.125f * 1.4426950408889634f;  // 1/sqrt(64) * log2(e)
    const float* src; half_t* dst; float sc;
    if (i < 131072) { src = q + (size_t)i * 8; dst = ws + WS_QS + (size_t)i * 8; sc = QS; }
    else { const int j = i - 131072; src = k + (size_t)j * 8; dst = ws + WS_KB + (size_t)j * 8; sc = 1.0f; }
    const float4 a = ((const float4*)src)[0];
    const float4 bb = ((const float4*)src)[1];
    half_t tt[8];
    tt[0] = (half_t)(a.x * sc);  tt[1] = (half_t)(a.y * sc);
    tt[2] = (half_t)(a.z * sc);  tt[3] = (half_t)(a.w * sc);
    tt[4] = (half_t)(bb.x * sc); tt[5] = (half_t)(bb.y * sc);
    tt[6] = (half_t)(bb.z * sc); tt[7] = (half_t)(bb.w * sc);
    *(int4*)dst = *(int4*)tt;
    return;
  }
  if (b >= 4384) {
    if (b < 4640) {                       // zero d_out
      float4* o = (float4*)out;
      const int base = (b - 4384) * 1024 + t;
#pragma unroll
      for (int u = 0; u < 4; ++u) o[base + u * 256] = float4{0, 0, 0, 0};
    } else {                              // zero z region
      float4* z = (float4*)((float*)(ws + WS_Z));
      const int base = (b - 4640) * 1024 + t;
#pragma unroll
      for (int u = 0; u < 4; ++u) z[base + u * 256] = float4{0, 0, 0, 0};
    }
    return;
  }
  const bool isV = (b < 4352);
  int bh = 0, kt = 0, b3 = 0;
  const float* src; int sstride;
  if (isV) {
    const int b2 = b - 3072;
    bh = b2 / 40; kt = b2 % 40;
    src = v + (size_t)(bh * 2560 + kt * 64) * 64; sstride = 64;
  } else {
    b3 = b - 4352;
    src = pe + (size_t)b3 * 64; sstride = 2048;
  }
  const int rr = t >> 4, cq = (t & 15) * 4;
#pragma unroll
  for (int p = 0; p < 4; ++p) {
    const float4 x = *(const float4*)(src + (size_t)(p * 16 + rr) * sstride + cq);
    *(float4*)(ls + (p * 16 + rr) * 72 + cq) = x;
  }
  __syncthreads();
  const int oc = t >> 2, ch = t & 3;
  half_t tmp[16];
#pragma unroll
  for (int i2 = 0; i2 < 16; ++i2) tmp[i2] = (half_t)ls[(ch * 16 + i2) * 72 + oc];
  half_t* o;
  if (isV) {
    o = ws + WS_VC + (size_t)bh * 163840 + ((kt << 1) + (ch >> 1)) * 2048 + oc * 32 + ((ch & 1) << 4);
  } else {
    o = ws + WS_PET + ((size_t)b3 * 64 + oc) * 64 + ch * 16;
  }
  ((int4*)o)[0] = ((int4*)tmp)[0];
  ((int4*)o)[1] = ((int4*)tmp)[1];
}

// ---------- K2: 32x32-MFMA split-K attention ----------
// grid 512 = 32bh x 4 m-blocks(128 rows) x 4 K-splits (17 chunks each);
// block 256 (4 waves); wave w computes a 32-row x 32-key tile per step via
// v_mfma_f32_32x32x16_f16: S^T = K.Q^T (4 MFMA), PV O^T = V^T.P (4 MFMA),
// PE bias (4 MFMA/step, one 32-l window). ~55% fewer MFMA instrs, ~40% fewer
// LDS ops, ~35% fewer VALU per unit work than R13 — attacks the measured
// invariant (~550 CU-cycles per 16x32 quantum, insensitive to occupancy).
// Layouts (32x32x16): A[m=lane&31][k=8*(lane>>5)+j]; B[k=8*(lane>>5)+j][n=lane&31];
// C: col=lane&31, row=(reg&3)+8*(reg>>2)+4*(lane>>5).
// Em strip (ring 64, u=(l+m)&63): scalar b16 writes (wrap-safe), b64 reads
// (no-wrap: read base = B+8q+4h is a multiple of 4). P strip [m][k] pad-40:
// b64 quad writes, b128 B-frag reads.
// LDS: K 2x4608 | Vc 2x5120 | Em 4x4352 | P 4x2560 = 47,104 B.
__global__ __launch_bounds__(256, 2) void attn_kernel(
    const half_t* __restrict__ ws, const float* __restrict__ cvp,
    float* __restrict__ out, float* __restrict__ zmA) {

  __shared__ __align__(16) char smem[47104];
  half_t* lsh = (half_t*)smem;

  const int tid  = threadIdx.x;
  const int lane = tid & 63;
  const int w    = tid >> 6;                    // wave 0..3
  const int c32  = lane & 31;                   // MFMA col (query m / key / d)
  const int h    = lane >> 5;                   // half-wave

  const int id = blockIdx.x;                    // 512
  const int bh = ((id & 7) << 2) | (id >> 7);   // XCD-aware
  const int mid = (id >> 3) & 15;
  const int mb = mid & 3, sp = mid >> 2;
  const int m0 = mb << 7;                       // 128 rows per block
  const int g0 = sp * 17;                       // chunks [g0, g0+17)

  const float cvl = cvp[bh & 7] * 2048.0f - 2047.0f;  // mask = clamp((l+cvl)/64+1,0,1)
  const float cvO = cvl * 0.015625f + 1.0f;

  const half_t* kb  = ws + WS_KB + (size_t)bh * (kKL * kD);
  const half_t* vcb = ws + WS_VC + (size_t)bh * (kKL * kD);
  const half_t* pet = ws + WS_PET;

  // Q B-frags: B[k=d=16t+8h+j][n=m=c32], t=0..3
  const half_t* qrow = ws + WS_QS + (size_t)(bh * kM + m0 + 32 * w + c32) * kD;
  half8 bq[4];
#pragma unroll
  for (int t = 0; t < 4; ++t) bq[t] = *(const half8*)(qrow + t * 16 + h * 8);

  // LDS (halves): K ring 2x2304 @0 | Vc ring 2x2560 @4608 | Em 4x2176 @9728 | P 4x1280 @18432
  half_t* stf = lsh + 9728 + w * 2176 + c32 * 68;     // Em strip row m=c32
  half_t* pw  = lsh + 18432 + w * 1280;               // P strip [m=32][40]

  int4 stgK, stgV;
  auto issueKV = [&](int gg) {
    const int r = tid >> 3, seg = tid & 7;
    const int krow = m0 + (gg << 5) + r;               // max 2559
    stgK = *(const int4*)(kb + (size_t)krow * kD + seg * 8);
    const int vch = (m0 >> 5) + gg;                    // max 79
    stgV = *(const int4*)(vcb + (size_t)vch * 2048 + tid * 8);
  };
  auto commitKV = [&](int gg) {
    const int sK = (gg & 1) * 2304;
    const int sV = 4608 + (gg & 1) * 2560;
    const int r = tid >> 3, seg = tid & 7;
    *(int4*)(lsh + sK + r * 72 + seg * 8) = stgK;
    const int d = tid >> 2, ks = (tid & 3) * 8;
    *(int4*)(lsh + sV + d * 40 + ks) = stgV;
  };

  // PE bias window [wb, wb+32): C[row=l-wb][col=m], A from global peT (divergent
  // but off critical path; R8/R9 A/B: ~= LDS-ring cost)
  auto peWindow = [&](int wb) -> f32x16 {
    int l = wb + c32; l = l < 0 ? 0 : (l > kL - 1 ? kL - 1 : l);
    const half_t* pp = pet + (size_t)l * kD;
    f32x16 a = {};
#pragma unroll
    for (int t = 0; t < 4; ++t) {
      const half8 p = *(const half8*)(pp + t * 16 + h * 8);
      a = MFMA_S(p, bq[t], a);
    }
    return a;
  };
  auto stripWrite = [&](int wb, const f32x16& a) {
    const int allone  = (wb >= 0) && (wb + 31 <= kL - 1) && (wb + cvl >= 0.0f);
    const int allzero = (wb > kL - 1) || (wb + 31 < 0) || ((float)(wb + 31) + cvl <= -64.0f);
#pragma unroll
    for (int reg = 0; reg < 16; ++reg) {
      const int lr = (reg & 3) + 8 * (reg >> 2) + 4 * h;
      const int l  = wb + lr;
      const float bt = a[reg] * 0.6931472f;
      float e = __builtin_fmaf(bt, 0.16666667f, 0.5f);   // exp2(bias) poly
      e = __builtin_fmaf(e, bt, 1.0f);
      e = __builtin_fmaf(e, bt, 1.0f);
      float em;
      if (allzero) em = 0.0f;
      else if (allone) em = e;
      else {
        const float mk = fminf(fmaxf((float)l * 0.015625f + cvO, 0.0f), 1.0f);
        em = ((unsigned)l < (unsigned)kL) ? e * mk : 0.0f;
      }
      stf[(l + c32) & 63] = (half_t)em;
    }
  };

  // ---- prime: K/V chunk g0 + Em windows [B0-32, B0) and [B0, B0+32) ----
  issueKV(g0);
  const int B0 = (g0 << 5) - 32 * w;
  stripWrite(B0 - 32, peWindow(B0 - 32));
  stripWrite(B0,      peWindow(B0));
  commitKV(g0);
  __syncthreads();

  float zmc = 0.0f;
  f32x16 o0 = {}, o1 = {};                      // O^T d in [0,32) / [32,64)

  for (int t = 0; t < 17; ++t) {
    const int g = g0 + t;
    const bool more = (t < 16);
    if (more) issueKV(g + 1);

    const int sK = (g & 1) * 2304;
    const int sV = 4608 + (g & 1) * 2560;
    const int B = (g << 5) - 32 * w;            // l of key0 vs m=c32=0

    // K A-frags: A[m=key=c32][k=16t+8h+j]
    half8 ak[4];
#pragma unroll
    for (int kt = 0; kt < 4; ++kt)
      ak[kt] = *(const half8*)(lsh + sK + c32 * 72 + kt * 16 + h * 8);

    // Em quads (written at previous step): u = B + 8q + 4h (+r), mult of 4 -> no wrap
    half4 emq[4];
#pragma unroll
    for (int q = 0; q < 4; ++q)
      emq[q] = *(const half4*)(stf + ((B + 8 * q + 4 * h) & 63));

    // V^T A-frags: A[m=d-32dh=c32][k=16kt+8h+j]
    half8 av[2][2];
#pragma unroll
    for (int dh = 0; dh < 2; ++dh)
#pragma unroll
      for (int kt = 0; kt < 2; ++kt)
        av[dh][kt] = *(const half8*)(lsh + sV + (32 * dh + c32) * 40 + kt * 16 + h * 8);

    // ---- S^T = K.Q^T ----
    f32x16 s = {};
#pragma unroll
    for (int kt = 0; kt < 4; ++kt) s = MFMA_S(ak[kt], bq[kt], s);

    // ---- softmax: pm = exp2(s) * Em; P -> LDS strip (B-frag layout) ----
    float pm[16];
#pragma unroll
    for (int reg = 0; reg < 16; ++reg) {
      pm[reg] = __builtin_amdgcn_exp2f(s[reg]) * (float)emq[reg >> 2][reg & 3];
      zmc += pm[reg];
    }
#pragma unroll
    for (int q = 0; q < 4; ++q) {
      const half4 pq = { (half_t)pm[q * 4], (half_t)pm[q * 4 + 1],
                         (half_t)pm[q * 4 + 2], (half_t)pm[q * 4 + 3] };
      *(half4*)(pw + c32 * 40 + 8 * q + 4 * h) = pq;   // P[m=c32][k=8q+4h+r]
    }

    // ---- PV: O^T[d][m] += V^T.P ----
    const half8 pb0 = *(const half8*)(pw + c32 * 40 + 0  + h * 8);
    const half8 pb1 = *(const half8*)(pw + c32 * 40 + 16 + h * 8);
    o0 = MFMA_S(av[0][0], pb0, o0);
    o0 = MFMA_S(av[0][1], pb1, o0);
    o1 = MFMA_S(av[1][0], pb0, o1);
    o1 = MFMA_S(av[1][1], pb1, o1);

    // ---- Em window for t+1 (after reads): [B+32, B+64) ----
    if (more) {
      stripWrite(B + 32, peWindow(B + 32));
      commitKV(g + 1);
    }
    __syncthreads();
  }

  // ---- epilogue ----
  __syncthreads();                              // safe to overlay LDS
  float* Ow = (float*)smem + (size_t)w * 2176;  // [32 m][stride 68] f32
#pragma unroll
  for (int q = 0; q < 4; ++q) {
    *(f32x4*)(Ow + c32 * 68 + 0  + 8 * q + 4 * h) =
        f32x4{o0[q * 4], o0[q * 4 + 1], o0[q * 4 + 2], o0[q * 4 + 3]};
    *(f32x4*)(Ow + c32 * 68 + 32 + 8 * q + 4 * h) =
        f32x4{o1[q * 4], o1[q * 4 + 1], o1[q * 4 + 2], o1[q * 4 + 3]};
  }
  zmc += __shfl_xor(zmc, 32);
  if (lane < 32) {
    const int row = bh * kM + m0 + 32 * w + c32;
    atomicAdd(&zmA[row], zmc);
  }
  const int rowbase = bh * kM + m0 + 32 * w;
  for (int rr = 0; rr < 32; ++rr)
    atomicAdd(out + (size_t)(rowbase + rr) * kD + lane, Ow[rr * 68 + lane]);
}

// ---------- K3: normalize ----------
__global__ __launch_bounds__(256) void norm_kernel(const float* __restrict__ zmA,
    float* __restrict__ out) {
  const int i = blockIdx.x * 256 + threadIdx.x;   // 262,144
  const int row = i >> 4, d4 = (i & 15) << 2;
  const float inv = 1.0f / (zmA[row] + 1e-20f);
  float4* p = (float4*)(out + (size_t)row * 64 + d4);
  float4 v = *p;
  v.x *= inv; v.y *= inv; v.z *= inv; v.w *= inv;
  *p = v;
}

extern "C" void kernel_launch(void* const* d_in, const int* in_sizes, int n_in,
                              void* d_out, int out_size, void* d_ws, size_t ws_size,
                              hipStream_t stream) {
  (void)in_sizes; (void)n_in; (void)out_size; (void)ws_size;
  const float* q  = (const float*)d_in[0];
  const float* k  = (const float*)d_in[1];
  const float* v  = (const float*)d_in[2];
  const float* pe = (const float*)d_in[3];
  const float* cv = (const float*)d_in[4];
  half_t* ws = (half_t*)d_ws;   // needs ~23.6 MB
  float* out = (float*)d_out;
  float* zmA = (float*)(ws + WS_Z);

  prep_kernel<<<4648, 256, 0, stream>>>(q, k, v, pe, ws, out);
  attn_kernel<<<512, 256, 0, stream>>>(ws, cv, out, zmA);
  norm_kernel<<<1024, 256, 0, stream>>>(zmA, out);
}